// Round 1
// baseline (71.677 us; speedup 1.0000x reference)
//
#include <hip/hip_runtime.h>
#include <hip/hip_bf16.h>
#include <stdint.h>

#define Bn 256
#define Sn 512
#define Hn 768
#define Pn 32
#define Kn 3072   // 4*H

typedef __attribute__((ext_vector_type(8))) short short8;
typedef __attribute__((ext_vector_type(4))) float f32x4;

__device__ __forceinline__ unsigned short f2bf(float f) {
    union { float f; unsigned int u; } v;
    v.f = f;
    unsigned int r = v.u + 0x7FFFu + ((v.u >> 16) & 1u);  // round-to-nearest-even
    return (unsigned short)(r >> 16);
}

// K1: masked-mean pool + cls extract + concat + L2-normalize -> bf16 (256 x 3072)
// layout of combined row: [pool_p (0..767), cls_p (768..1535), pool_m (1536..2303), cls_m (2304..3071)]
__global__ __launch_bounds__(384) void k_pool_norm(
    const float* __restrict__ pv, const float* __restrict__ mv,
    const int* __restrict__ apos, unsigned short* __restrict__ normb)
{
    const int b   = blockIdx.x;
    const int tid = threadIdx.x;

    __shared__ int   spos[Pn];
    __shared__ float swsum[6];
    __shared__ float sinv;

    if (tid < Pn) spos[tid] = apos[b * Pn + tid];
    __syncthreads();

    int cnt = 0;
    #pragma unroll
    for (int p = 0; p < Pn; ++p) cnt += (spos[p] >= 0) ? 1 : 0;
    const float invc = 1.0f / (float)(cnt < 1 ? 1 : cnt);

    const float* src  = (tid < 192) ? pv : mv;
    const int    col4 = (tid < 192) ? tid : (tid - 192);
    const size_t base = (size_t)b * ((size_t)Sn * Hn) + (size_t)col4 * 4;

    float4 acc = make_float4(0.f, 0.f, 0.f, 0.f);
    #pragma unroll
    for (int p = 0; p < Pn; ++p) {
        int q = spos[p];            // uniform across block -> no divergence
        if (q >= 0) {
            float4 g = *(const float4*)(src + base + (size_t)q * Hn);
            acc.x += g.x; acc.y += g.y; acc.z += g.z; acc.w += g.w;
        }
    }
    float4 cls  = *(const float4*)(src + base);   // row 0
    float4 pool = make_float4(acc.x * invc, acc.y * invc, acc.z * invc, acc.w * invc);

    float sq = pool.x*pool.x + pool.y*pool.y + pool.z*pool.z + pool.w*pool.w
             + cls.x*cls.x  + cls.y*cls.y  + cls.z*cls.z  + cls.w*cls.w;
    #pragma unroll
    for (int off = 32; off > 0; off >>= 1) sq += __shfl_down(sq, off);
    if ((tid & 63) == 0) swsum[tid >> 6] = sq;
    __syncthreads();
    if (tid == 0) {
        float t = swsum[0] + swsum[1] + swsum[2] + swsum[3] + swsum[4] + swsum[5];
        sinv = 1.0f / fmaxf(sqrtf(t), 1e-12f);
    }
    __syncthreads();
    const float s = sinv;

    const int sect = (tid < 192) ? 0 : 2;
    unsigned short* o = normb + (size_t)b * Kn;
    ushort4 w0, w1;
    w0.x = f2bf(pool.x * s); w0.y = f2bf(pool.y * s); w0.z = f2bf(pool.z * s); w0.w = f2bf(pool.w * s);
    w1.x = f2bf(cls.x  * s); w1.y = f2bf(cls.y  * s); w1.z = f2bf(cls.z  * s); w1.w = f2bf(cls.w  * s);
    *(ushort4*)(o + sect * Hn + col4 * 4)       = w0;
    *(ushort4*)(o + (sect + 1) * Hn + col4 * 4) = w1;
}

// K2: out1[256,768] = norm(bf16) @ fc1_w^T + fc1_b, via 16x16x32 bf16 MFMA.
// One 16x16 output tile per wave over full K=3072. 768 waves = 192 blocks x 256.
// A frag: row = lane%16, k = (lane/16)*8 + i  (8 contiguous bf16 = 16B/lane)
// B frag: col(h) = lane%16, k = (lane/16)*8 + i  (fc1_w row-major along k; f32->bf16 in-reg)
// D: col = lane&15, row = (lane>>4)*4 + i   [guide §3, m89-verified]
__global__ __launch_bounds__(256) void k_gemm(
    const unsigned short* __restrict__ normb, const float* __restrict__ w1,
    const float* __restrict__ b1, float* __restrict__ out1)
{
    const int wave = (blockIdx.x * 256 + threadIdx.x) >> 6;   // 0..767
    const int lane = threadIdx.x & 63;
    const int m0 = (wave & 15) * 16;
    const int h0 = (wave >> 4) * 16;
    const int r  = lane & 15;
    const int g  = lane >> 4;

    const unsigned short* ap = normb + (size_t)(m0 + r) * Kn + g * 8;
    const float*          bp = w1    + (size_t)(h0 + r) * Kn + g * 8;

    f32x4 acc = {0.f, 0.f, 0.f, 0.f};
    #pragma unroll 4
    for (int kk = 0; kk < 96; ++kk) {
        short8 a = *(const short8*)ap;
        float4 wa = *(const float4*)bp;
        float4 wb = *(const float4*)(bp + 4);
        short8 bb;
        bb[0] = (short)f2bf(wa.x); bb[1] = (short)f2bf(wa.y);
        bb[2] = (short)f2bf(wa.z); bb[3] = (short)f2bf(wa.w);
        bb[4] = (short)f2bf(wb.x); bb[5] = (short)f2bf(wb.y);
        bb[6] = (short)f2bf(wb.z); bb[7] = (short)f2bf(wb.w);
        acc = __builtin_amdgcn_mfma_f32_16x16x32_bf16(a, bb, acc, 0, 0, 0);
        ap += 32; bp += 32;
    }
    const float bias = b1[h0 + r];
    float* o = out1 + (size_t)(m0 + g * 4) * Hn + h0 + r;
    #pragma unroll
    for (int i = 0; i < 4; ++i) o[(size_t)i * Hn] = acc[i] + bias;
}

// K3: BN stats over batch (256) per feature (768) -> scale/shift. 12 blocks x 256.
__global__ __launch_bounds__(256) void k_bnstats(
    const float* __restrict__ out1, const float* __restrict__ gamma,
    const float* __restrict__ beta, float* __restrict__ scaleF,
    float* __restrict__ shiftF)
{
    const int lane64 = threadIdx.x & 63;
    const int wv = threadIdx.x >> 6;             // 0..3, each wave handles 64 rows
    const int f = blockIdx.x * 64 + lane64;
    float s = 0.f, s2 = 0.f;
    for (int rr = wv * 64; rr < wv * 64 + 64; ++rr) {
        float x = out1[(size_t)rr * Hn + f];
        s += x; s2 += x * x;
    }
    __shared__ float ls[4][64];
    __shared__ float ls2[4][64];
    ls[wv][lane64] = s; ls2[wv][lane64] = s2;
    __syncthreads();
    if (threadIdx.x < 64) {
        int ff = blockIdx.x * 64 + threadIdx.x;
        float ts  = ls[0][threadIdx.x] + ls[1][threadIdx.x] + ls[2][threadIdx.x] + ls[3][threadIdx.x];
        float ts2 = ls2[0][threadIdx.x] + ls2[1][threadIdx.x] + ls2[2][threadIdx.x] + ls2[3][threadIdx.x];
        float mean = ts * (1.0f / 256.0f);
        float var  = fmaxf(ts2 * (1.0f / 256.0f) - mean * mean, 0.0f);
        float inv  = 1.0f / sqrtf(var + 1e-5f);
        float sc   = inv * gamma[ff];
        scaleF[ff] = sc;
        shiftF[ff] = beta[ff] - mean * sc;
    }
}

// K4: per-row BN-apply + ReLU + fc2 dot -> out[256]. 256 blocks x 256.
__global__ __launch_bounds__(256) void k_fc2(
    const float* __restrict__ out1, const float* __restrict__ scaleF,
    const float* __restrict__ shiftF, const float* __restrict__ w2,
    const float* __restrict__ b2, float* __restrict__ out)
{
    const int b = blockIdx.x, tid = threadIdx.x;
    float acc = 0.f;
    #pragma unroll
    for (int j = 0; j < 3; ++j) {
        int h = tid + j * 256;
        float x = out1[(size_t)b * Hn + h];
        float v = fmaxf(x * scaleF[h] + shiftF[h], 0.f);
        acc += v * w2[h];
    }
    #pragma unroll
    for (int off = 32; off > 0; off >>= 1) acc += __shfl_down(acc, off);
    __shared__ float ws4[4];
    if ((tid & 63) == 0) ws4[tid >> 6] = acc;
    __syncthreads();
    if (tid == 0) out[b] = ws4[0] + ws4[1] + ws4[2] + ws4[3] + b2[0];
}

extern "C" void kernel_launch(void* const* d_in, const int* in_sizes, int n_in,
                              void* d_out, int out_size, void* d_ws, size_t ws_size,
                              hipStream_t stream)
{
    const float* pv    = (const float*)d_in[0];
    const float* mv    = (const float*)d_in[1];
    const int*   apos  = (const int*)d_in[2];   // JAX x64 disabled -> int32
    const float* w1    = (const float*)d_in[3];
    const float* b1    = (const float*)d_in[4];
    const float* w2    = (const float*)d_in[5];
    const float* b2    = (const float*)d_in[6];
    const float* gamma = (const float*)d_in[7];
    const float* beta  = (const float*)d_in[8];
    float* out = (float*)d_out;

    char* ws = (char*)d_ws;
    unsigned short* normb  = (unsigned short*)ws;                 // 256*3072*2 = 1572864 B
    float*          out1   = (float*)(ws + 1572864);              // 256*768*4  =  786432 B
    float*          scaleF = (float*)(ws + 1572864 + 786432);     // 768*4
    float*          shiftF = (float*)(ws + 1572864 + 786432 + 4096);

    hipLaunchKernelGGL(k_pool_norm, dim3(Bn),  dim3(384), 0, stream, pv, mv, apos, normb);
    hipLaunchKernelGGL(k_gemm,      dim3(192), dim3(256), 0, stream, normb, w1, b1, out1);
    hipLaunchKernelGGL(k_bnstats,   dim3(12),  dim3(256), 0, stream, out1, gamma, beta, scaleF, shiftF);
    hipLaunchKernelGGL(k_fc2,       dim3(Bn),  dim3(256), 0, stream, out1, scaleF, shiftF, w2, b2, out);
}

// Round 2
// 37.709 us; speedup vs baseline: 1.9008x; 1.9008x over previous
//
#include <hip/hip_runtime.h>
#include <hip/hip_bf16.h>
#include <stdint.h>

#define Bn 256
#define Sn 512
#define Hn 768
#define Pn 32
#define Kn 3072   // 4*H

typedef __attribute__((ext_vector_type(8))) short short8;
typedef __attribute__((ext_vector_type(4))) float f32x4;

__device__ __forceinline__ unsigned short f2bf(float f) {
    union { float f; unsigned int u; } v;
    v.f = f;
    unsigned int r = v.u + 0x7FFFu + ((v.u >> 16) & 1u);  // RNE
    return (unsigned short)(r >> 16);
}

__device__ __forceinline__ void gload_lds16(const void* src, void* lds) {
    __builtin_amdgcn_global_load_lds(
        (const __attribute__((address_space(1))) unsigned int*)src,
        (__attribute__((address_space(3))) unsigned int*)lds, 16, 0, 0);
}

// K1: masked-mean pool + cls + concat + L2-normalize -> bf16 normb[256][3072]
//     + tail: convert fc1_w (f32) -> w1b (bf16), grid-stride.
__global__ __launch_bounds__(384) void k_pool_norm(
    const float* __restrict__ pv, const float* __restrict__ mv,
    const int* __restrict__ apos, unsigned short* __restrict__ normb,
    const float* __restrict__ w1, unsigned short* __restrict__ w1b)
{
    const int b   = blockIdx.x;
    const int tid = threadIdx.x;

    __shared__ int   spos[Pn];
    __shared__ float swsum[6];
    __shared__ float sinv;

    if (tid < Pn) spos[tid] = apos[b * Pn + tid];
    __syncthreads();

    int cnt = 0;
    #pragma unroll
    for (int p = 0; p < Pn; ++p) cnt += (spos[p] >= 0) ? 1 : 0;
    const float invc = 1.0f / (float)(cnt < 1 ? 1 : cnt);

    const float* src  = (tid < 192) ? pv : mv;
    const int    col4 = (tid < 192) ? tid : (tid - 192);
    const size_t base = (size_t)b * ((size_t)Sn * Hn) + (size_t)col4 * 4;

    float4 acc = make_float4(0.f, 0.f, 0.f, 0.f);
    #pragma unroll
    for (int p = 0; p < Pn; ++p) {
        int q = spos[p];
        if (q >= 0) {
            float4 g = *(const float4*)(src + base + (size_t)q * Hn);
            acc.x += g.x; acc.y += g.y; acc.z += g.z; acc.w += g.w;
        }
    }
    float4 cls  = *(const float4*)(src + base);   // row 0
    float4 pool = make_float4(acc.x * invc, acc.y * invc, acc.z * invc, acc.w * invc);

    float sq = pool.x*pool.x + pool.y*pool.y + pool.z*pool.z + pool.w*pool.w
             + cls.x*cls.x  + cls.y*cls.y  + cls.z*cls.z  + cls.w*cls.w;
    #pragma unroll
    for (int off = 32; off > 0; off >>= 1) sq += __shfl_down(sq, off);
    if ((tid & 63) == 0) swsum[tid >> 6] = sq;
    __syncthreads();
    if (tid == 0) {
        float t = swsum[0] + swsum[1] + swsum[2] + swsum[3] + swsum[4] + swsum[5];
        sinv = 1.0f / fmaxf(sqrtf(t), 1e-12f);
    }
    __syncthreads();
    const float s = sinv;

    const int sect = (tid < 192) ? 0 : 2;
    unsigned short* o = normb + (size_t)b * Kn;
    ushort4 w0, w1v;
    w0.x = f2bf(pool.x * s); w0.y = f2bf(pool.y * s); w0.z = f2bf(pool.z * s); w0.w = f2bf(pool.w * s);
    w1v.x = f2bf(cls.x * s); w1v.y = f2bf(cls.y * s); w1v.z = f2bf(cls.z * s); w1v.w = f2bf(cls.w * s);
    *(ushort4*)(o + sect * Hn + col4 * 4)       = w0;
    *(ushort4*)(o + (sect + 1) * Hn + col4 * 4) = w1v;

    // --- tail: fc1_w f32 -> bf16 (768*3072 = 2359296 elems = 294912 chunks of 8) ---
    const int gtid = b * 384 + tid;               // 0..98303
    for (int c = gtid; c < 294912; c += 98304) {
        const float4 fa = *(const float4*)(w1 + (size_t)c * 8);
        const float4 fb = *(const float4*)(w1 + (size_t)c * 8 + 4);
        ushort4 ua, ub;
        ua.x = f2bf(fa.x); ua.y = f2bf(fa.y); ua.z = f2bf(fa.z); ua.w = f2bf(fa.w);
        ub.x = f2bf(fb.x); ub.y = f2bf(fb.y); ub.z = f2bf(fb.z); ub.w = f2bf(fb.w);
        *(ushort4*)(w1b + (size_t)c * 8)     = ua;
        *(ushort4*)(w1b + (size_t)c * 8 + 4) = ub;
    }
}

// K2: partial[ks][256][768] = normb @ w1b^T over K-chunk ks.
// 64x64 block tile, BK=64, 4 waves (2x2), each wave 32x32 via 2x2x2 mfma_16x16x32.
// LDS: XOR-swizzled (slot = kg ^ (row&7)); staged with global_load_lds width-16:
// linear LDS dest + inverse-swizzled global source (G21 both-sides rule).
#define KSPLIT 4
#define NSTEP 12   // 768 / 64
__global__ __launch_bounds__(256) void k_gemm(
    const unsigned short* __restrict__ A,   // normb [256][3072]
    const unsigned short* __restrict__ Bw,  // w1b   [768][3072]
    float* __restrict__ part)               // [4][256][768]
{
    __shared__ __align__(16) unsigned short Al[2][64 * 64];
    __shared__ __align__(16) unsigned short Bl[2][64 * 64];

    const int bid = blockIdx.x;
    const int ks = bid & 3;
    const int mt = (bid >> 2) & 3;
    const int nt = bid >> 4;                 // 0..11
    const int m0 = mt * 64, n0 = nt * 64, k0 = ks * 768;

    const int tid  = threadIdx.x;
    const int w    = tid >> 6, lane = tid & 63;
    const int r    = lane & 15, g = lane >> 4;
    const int wm   = w >> 1,  wn = w & 1;

    // staging: thread stages chunks id0, id1 for each operand
    const int id0 = w * 128 + lane;
    const int id1 = id0 + 64;
    const int row0 = id0 >> 3, kg0 = (id0 & 7) ^ (row0 & 7);
    const int row1 = id1 >> 3, kg1 = (id1 & 7) ^ (row1 & 7);

    const unsigned short* a0 = A  + (size_t)(m0 + row0) * Kn + k0 + kg0 * 8;
    const unsigned short* a1 = A  + (size_t)(m0 + row1) * Kn + k0 + kg1 * 8;
    const unsigned short* b0 = Bw + (size_t)(n0 + row0) * Kn + k0 + kg0 * 8;
    const unsigned short* b1 = Bw + (size_t)(n0 + row1) * Kn + k0 + kg1 * 8;

    const int dst0 = w * 1024;        // element offset of call-0 chunk base
    const int dst1 = dst0 + 512;      // call-1

    f32x4 acc[2][2] = {{{0.f,0.f,0.f,0.f},{0.f,0.f,0.f,0.f}},
                       {{0.f,0.f,0.f,0.f},{0.f,0.f,0.f,0.f}}};

    // prologue: stage step 0 into buf 0
    gload_lds16(a0, &Al[0][dst0]);
    gload_lds16(a1, &Al[0][dst1]);
    gload_lds16(b0, &Bl[0][dst0]);
    gload_lds16(b1, &Bl[0][dst1]);

    int cur = 0;
    for (int s = 0; s < NSTEP; ++s) {
        __syncthreads();   // drains vmcnt (stages) + lgkmcnt (prev reads)
        if (s + 1 < NSTEP) {
            const int ko = (s + 1) * 64;
            gload_lds16(a0 + ko, &Al[cur ^ 1][dst0]);
            gload_lds16(a1 + ko, &Al[cur ^ 1][dst1]);
            gload_lds16(b0 + ko, &Bl[cur ^ 1][dst0]);
            gload_lds16(b1 + ko, &Bl[cur ^ 1][dst1]);
        }
        #pragma unroll
        for (int kq = 0; kq < 2; ++kq) {
            short8 af[2], bf[2];
            #pragma unroll
            for (int ma = 0; ma < 2; ++ma) {
                const int row = wm * 32 + ma * 16 + r;
                const int slot = (kq * 4 + g) ^ (row & 7);
                af[ma] = *(const short8*)&Al[cur][row * 64 + slot * 8];
            }
            #pragma unroll
            for (int nb = 0; nb < 2; ++nb) {
                const int row = wn * 32 + nb * 16 + r;
                const int slot = (kq * 4 + g) ^ (row & 7);
                bf[nb] = *(const short8*)&Bl[cur][row * 64 + slot * 8];
            }
            #pragma unroll
            for (int ma = 0; ma < 2; ++ma)
                #pragma unroll
                for (int nb = 0; nb < 2; ++nb)
                    acc[ma][nb] = __builtin_amdgcn_mfma_f32_16x16x32_bf16(
                        af[ma], bf[nb], acc[ma][nb], 0, 0, 0);
        }
        cur ^= 1;
    }

    // store partials: D layout col=lane&15, row=(lane>>4)*4+i
    float* o = part + (size_t)ks * (Bn * Hn);
    #pragma unroll
    for (int ma = 0; ma < 2; ++ma) {
        #pragma unroll
        for (int nb = 0; nb < 2; ++nb) {
            const int orow = m0 + wm * 32 + ma * 16 + g * 4;
            const int ocol = n0 + wn * 32 + nb * 16 + r;
            #pragma unroll
            for (int i = 0; i < 4; ++i)
                o[(size_t)(orow + i) * Hn + ocol] = acc[ma][nb][i];
        }
    }
}

// K3: fold 4 K-partials -> out1 (bias cancels through BN), BN stats -> scale/shift.
// 48 blocks x 256 threads; block covers 16 features, thread (rg,fo) covers 16 rows.
__global__ __launch_bounds__(256) void k_bnfold(
    const float* __restrict__ part, const float* __restrict__ gamma,
    const float* __restrict__ beta, float* __restrict__ out1,
    float* __restrict__ scaleF, float* __restrict__ shiftF)
{
    const int blk = blockIdx.x;
    const int fo = threadIdx.x & 15, rg = threadIdx.x >> 4;
    const int f = blk * 16 + fo;
    const float* p0 = part + f;
    const float* p1 = p0 + Bn * Hn;
    const float* p2 = p1 + Bn * Hn;
    const float* p3 = p2 + Bn * Hn;

    float s = 0.f, s2 = 0.f;
    #pragma unroll
    for (int i = 0; i < 16; ++i) {
        const size_t off = (size_t)(rg * 16 + i) * Hn;
        const float y = p0[off] + p1[off] + p2[off] + p3[off];
        out1[off + f] = y;
        s += y; s2 += y * y;
    }
    __shared__ float S[16][16], S2[16][16];
    S[rg][fo] = s; S2[rg][fo] = s2;
    __syncthreads();
    if (threadIdx.x < 16) {
        const int ff = blk * 16 + threadIdx.x;
        float ts = 0.f, ts2 = 0.f;
        #pragma unroll
        for (int i = 0; i < 16; ++i) { ts += S[i][threadIdx.x]; ts2 += S2[i][threadIdx.x]; }
        const float mean = ts * (1.0f / 256.0f);
        const float var  = fmaxf(ts2 * (1.0f / 256.0f) - mean * mean, 0.0f);
        const float sc   = gamma[ff] / sqrtf(var + 1e-5f);
        scaleF[ff] = sc;
        shiftF[ff] = beta[ff] - mean * sc;
    }
}

// K4: per-row BN-apply + ReLU + fc2 dot -> out[256].
__global__ __launch_bounds__(256) void k_fc2(
    const float* __restrict__ out1, const float* __restrict__ scaleF,
    const float* __restrict__ shiftF, const float* __restrict__ w2,
    const float* __restrict__ b2, float* __restrict__ out)
{
    const int b = blockIdx.x, tid = threadIdx.x;
    float acc = 0.f;
    #pragma unroll
    for (int j = 0; j < 3; ++j) {
        const int h = tid + j * 256;
        const float x = out1[(size_t)b * Hn + h];
        const float v = fmaxf(x * scaleF[h] + shiftF[h], 0.f);
        acc += v * w2[h];
    }
    #pragma unroll
    for (int off = 32; off > 0; off >>= 1) acc += __shfl_down(acc, off);
    __shared__ float ws4[4];
    if ((tid & 63) == 0) ws4[tid >> 6] = acc;
    __syncthreads();
    if (tid == 0) out[b] = ws4[0] + ws4[1] + ws4[2] + ws4[3] + b2[0];
}

extern "C" void kernel_launch(void* const* d_in, const int* in_sizes, int n_in,
                              void* d_out, int out_size, void* d_ws, size_t ws_size,
                              hipStream_t stream)
{
    const float* pv    = (const float*)d_in[0];
    const float* mv    = (const float*)d_in[1];
    const int*   apos  = (const int*)d_in[2];
    const float* w1    = (const float*)d_in[3];
    const float* w2    = (const float*)d_in[5];
    const float* b2    = (const float*)d_in[6];
    const float* gamma = (const float*)d_in[7];
    const float* beta  = (const float*)d_in[8];
    float* out = (float*)d_out;

    char* ws = (char*)d_ws;
    unsigned short* normb  = (unsigned short*)ws;                    // 1,572,864 B
    unsigned short* w1b    = (unsigned short*)(ws + 1572864);        // 4,718,592 B
    float*          part   = (float*)(ws + 1572864 + 4718592);      // 3,145,728 B
    float*          out1   = (float*)(ws + 1572864 + 4718592 + 3145728);      // 786,432 B
    float*          scaleF = (float*)(ws + 1572864 + 4718592 + 3145728 + 786432);
    float*          shiftF = (float*)(ws + 1572864 + 4718592 + 3145728 + 786432 + 4096);

    hipLaunchKernelGGL(k_pool_norm, dim3(Bn),  dim3(384), 0, stream, pv, mv, apos, normb, w1, w1b);
    hipLaunchKernelGGL(k_gemm,      dim3(192), dim3(256), 0, stream, normb, w1b, part);
    hipLaunchKernelGGL(k_bnfold,    dim3(48),  dim3(256), 0, stream, part, gamma, beta, out1, scaleF, shiftF);
    hipLaunchKernelGGL(k_fc2,       dim3(Bn),  dim3(256), 0, stream, out1, scaleF, shiftF, w2, b2, out);
}